// Round 6
// baseline (90.471 us; speedup 1.0000x reference)
//
#include <hip/hip_runtime.h>
#include <math.h>

// pred: (1,16,384,384) fp32, labels int32 same shape, area fp32[256]
constexpr int ZN = 16, YN = 384, XN = 384;
constexpr int NZ = 17, NY = 385, NX = 385;   // node grid
constexpr int NP = NY * NX;                  // 148225 nodes per z-slab
// wave = (y, xchunk in [0,6), zhalf in {0,1}); 385*12 = 4620 waves, 4 waves/block
constexpr int NWAVES = NY * 12;
constexpr int BLOCKS = NWAVES / 4;           // 1155

struct Col { float s0, s1, q; int b; };      // sigmoids (y-1, y), sum d^2, bits L0|L1<<1|P0<<2|P1<<3

__device__ __forceinline__ float sigm(float p) {
    return __fdividef(1.f, 1.f + __expf(-p));
}

__global__ __launch_bounds__(256) void sd_main(
        const float* __restrict__ pred,
        const int*   __restrict__ labels,
        const float* __restrict__ area,
        float*       __restrict__ partial)   // [num BLOCKS][den BLOCKS][vol BLOCKS]
{
    // Re-indexed LUT: idx = (own_column_nibble << 4) | prev_column_nibble,
    // nibble bit r = 2dz+dy; original corner k = dz*4+dy*2+dx (dx: 0=prev col, 1=own col)
    __shared__ float s_area[256];
    {
        const int t = threadIdx.x;
        const int own = t >> 4, prv = t & 15;
        int code = 0;
#pragma unroll
        for (int r = 0; r < 4; ++r)
            code |= (((prv >> r) & 1) << (2 * r)) | (((own >> r) & 1) << (2 * r + 1));
        s_area[t] = area[code];
    }
    __syncthreads();

    const int lane = threadIdx.x & 63;
    const int wid  = blockIdx.x * 4 + (threadIdx.x >> 6);
    const int czh  = wid / NY;               // 0..11
    const int y    = wid - czh * NY;         // node row y: 0..384
    const int c    = czh >> 1;               // x-chunk 0..5
    const int zh   = czh & 1;                // z-half

    float num = 0.f, den = 0.f, vol = 0.f;

    const bool v0 = (y >= 1);                // voxel row yy=y-1 valid
    const bool v1 = (y <= YN - 1);           // voxel row yy=y   valid
    const int  r0 = (y - 1) * XN;
    const int  r1 = y * XN;
    const int  x  = c * 64 + lane;           // own voxel column (0..383)
    const int  xe = c * 64 - 1;              // lane-0 extra column (chunk boundary)
    const bool ev = (c > 0);

    // load + sigmoid one voxel z-row pair for one column
    auto pp = [&](int zz, int col, bool cok) -> Col {
        Col r; r.s0 = 0.f; r.s1 = 0.f; r.q = 0.f; r.b = 0;
        if (((unsigned)zz < (unsigned)ZN) & cok) {
            const int sb = zz * (YN * XN) + col;
            if (v0) {
                const float p = pred[sb + r0]; const int l = labels[sb + r0];
                const float s = sigm(p);
                const float d = s - (float)l;
                r.s0 = s; r.q = d * d;
                r.b  = l | ((int)(p > 0.f) << 2);
            }
            if (v1) {
                const float p = pred[sb + r1]; const int l = labels[sb + r1];
                const float s = sigm(p);
                const float d = s - (float)l;
                r.s1 = s; r.q += d * d;
                r.b |= (l << 1) | ((int)(p > 0.f) << 3);
            }
        }
        return r;
    };

    auto node = [&](float ps0, float ps1, float ps2, float ps3, float pq, int pL, int pP,
                    float os0, float os1, float os2, float os3, float oq, int oL, int oP) {
        const int idxL = (oL << 4) | pL;
        const int idxP = (oP << 4) | pP;
        const float la = s_area[idxL];
        const float pa = s_area[idxP];
        num = fmaf(2.f * la, 1.f - (pq + oq) * 0.125f, num);
        den += la + pa;
        if (idxL == 0 || idxL == 255) {      // interior: labels uniform (~0.8% of nodes)
            const bool one = (idxL == 255);
            float b = __logf(fmaxf(one ? ps0 : 1.f - ps0, 1e-12f))
                    + __logf(fmaxf(one ? ps1 : 1.f - ps1, 1e-12f))
                    + __logf(fmaxf(one ? ps2 : 1.f - ps2, 1e-12f))
                    + __logf(fmaxf(one ? ps3 : 1.f - ps3, 1e-12f))
                    + __logf(fmaxf(one ? os0 : 1.f - os0, 1e-12f))
                    + __logf(fmaxf(one ? os1 : 1.f - os1, 1e-12f))
                    + __logf(fmaxf(one ? os2 : 1.f - os2, 1e-12f))
                    + __logf(fmaxf(one ? os3 : 1.f - os3, 1e-12f));
            vol -= b;
        }
    };

    // State: own old z-row pair (o), prev-column old pair (qs0,qs1,pqo,pbo)
    Col o; o.s0 = 0.f; o.s1 = 0.f; o.q = 0.f; o.b = 0;
    float qs0 = 0.f, qs1 = 0.f, pqo = 0.f; int pbo = 0;

    if (zh) {                                // preamble: old pair = voxel z-row 8
        o = pp(8, x, true);
        Col oe; oe.s0 = oe.s1 = oe.q = 0.f; oe.b = 0;
        if (lane == 0) oe = pp(8, xe, ev);
        qs0 = __shfl_up(o.s0, 1); qs1 = __shfl_up(o.s1, 1);
        pqo = __shfl_up(o.q, 1);  pbo = __shfl_up(o.b, 1);
        if (lane == 0) { qs0 = oe.s0; qs1 = oe.s1; pqo = oe.q; pbo = oe.b; }
    }

    auto body = [&](int z) {
        Col n = pp(z, x, true);              // zz=z (z==16 -> zeros via bounds check)
        Col ne; ne.s0 = ne.s1 = ne.q = 0.f; ne.b = 0;
        if (lane == 0) ne = pp(z, xe, ev);
        float pn0 = __shfl_up(n.s0, 1), pn1 = __shfl_up(n.s1, 1), pqn = __shfl_up(n.q, 1);
        int   pbn = __shfl_up(n.b, 1);
        if (lane == 0) { pn0 = ne.s0; pn1 = ne.s1; pqn = ne.q; pbn = ne.b; }

        const int oL = (o.b & 3) | ((n.b & 3) << 2);
        const int oP = ((o.b >> 2) & 3) | (((n.b >> 2) & 3) << 2);
        const int pL = (pbo & 3) | ((pbn & 3) << 2);
        const int pP = ((pbo >> 2) & 3) | (((pbn >> 2) & 3) << 2);

        node(qs0, qs1, pn0, pn1, pqo + pqn, pL, pP,
             o.s0, o.s1, n.s0, n.s1, o.q + n.q, oL, oP);

        if (c == 5 && lane == 63) {          // node x=384: prev = own column, own = padding
            node(o.s0, o.s1, n.s0, n.s1, o.q + n.q, oL, oP,
                 0.f, 0.f, 0.f, 0.f, 0.f, 0, 0);
        }
        o = n; qs0 = pn0; qs1 = pn1; pqo = pqn; pbo = pbn;
    };

    if (zh == 0) {
#pragma unroll
        for (int z = 0; z < 9; ++z) body(z);
    } else {
#pragma unroll
        for (int z = 9; z < 17; ++z) body(z);
    }

    // wave + block reduction
#pragma unroll
    for (int off = 32; off > 0; off >>= 1) {
        num += __shfl_down(num, off);
        den += __shfl_down(den, off);
        vol += __shfl_down(vol, off);
    }
    __shared__ float sn[4], sd_[4], sv[4];
    const int w = threadIdx.x >> 6;
    if (lane == 0) { sn[w] = num; sd_[w] = den; sv[w] = vol; }
    __syncthreads();
    if (threadIdx.x == 0) {
        partial[blockIdx.x]              = sn[0] + sn[1] + sn[2] + sn[3];
        partial[BLOCKS + blockIdx.x]     = sd_[0] + sd_[1] + sd_[2] + sd_[3];
        partial[2 * BLOCKS + blockIdx.x] = sv[0] + sv[1] + sv[2] + sv[3];
    }
}

__global__ __launch_bounds__(256) void sd_final(
        const float* __restrict__ partial, float* __restrict__ out)
{
    double n = 0.0, d = 0.0, v = 0.0;
    for (int b = threadIdx.x; b < BLOCKS; b += 256) {
        n += (double)partial[b];
        d += (double)partial[BLOCKS + b];
        v += (double)partial[2 * BLOCKS + b];
    }
#pragma unroll
    for (int off = 32; off > 0; off >>= 1) {
        n += __shfl_down(n, off);
        d += __shfl_down(d, off);
        v += __shfl_down(v, off);
    }
    __shared__ double sn[4], sd_[4], sv[4];
    const int lane = threadIdx.x & 63, w = threadIdx.x >> 6;
    if (lane == 0) { sn[w] = n; sd_[w] = d; sv[w] = v; }
    __syncthreads();
    if (threadIdx.x == 0) {
        const double num = sn[0] + sn[1] + sn[2] + sn[3];
        const double den = sd_[0] + sd_[1] + sd_[2] + sd_[3];
        const double vol = (sv[0] + sv[1] + sv[2] + sv[3]) / (8.0 * (double)NP);
        const double dice = 1.0 - (num + 1e-3) / (den + 1e-3);
        out[0] = (float)(dice + vol);
    }
}

extern "C" void kernel_launch(void* const* d_in, const int* in_sizes, int n_in,
                              void* d_out, int out_size, void* d_ws, size_t ws_size,
                              hipStream_t stream)
{
    const float* pred   = (const float*)d_in[0];
    const int*   labels = (const int*)d_in[1];
    const float* area   = (const float*)d_in[2];
    float* out     = (float*)d_out;
    float* partial = (float*)d_ws;   // 3*BLOCKS floats, fully overwritten each call

    sd_main<<<BLOCKS, 256, 0, stream>>>(pred, labels, area, partial);
    sd_final<<<1, 256, 0, stream>>>(partial, out);
}